// Round 4
// baseline (1098.302 us; speedup 1.0000x reference)
//
#include <hip/hip_runtime.h>

typedef __attribute__((ext_vector_type(8))) __bf16 bf16x8;
typedef __attribute__((ext_vector_type(4))) float f32x4;
typedef __attribute__((ext_vector_type(4))) int i32x4;

#define GRID 1024
#define BLOCK 512
#define ITERS 8   // 4 batch rows per iter -> 32 rows per block

// swizzle for 128-col bf16 LDS tiles
__device__ __forceinline__ int swz(int row, int col) {
    return row * 128 + (col ^ ((row & 7) << 3));
}

__device__ __forceinline__ int cvt_pk_bf16(float lo, float hi) {
    int r;
    asm("v_cvt_pk_bf16_f32 %0, %1, %2" : "=v"(r) : "v"(lo), "v"(hi));
    return r;
}

// ws layout (bytes):
//   0      : W1p bf16 [128][32]  (k<15: W1, k==15: b1 bias-fold, k>=16: 0)
//   8192   : W2p bf16 [128][128] (= W2 row-major, [e][d])
//   40960  : W3p bf16 [128][128]
//   73728  : Mp  bf16 [128][128]  M[d][f] = sum_e Ur[e][d]*Uq[e][f]
//   106496 : end

__global__ __launch_bounds__(128)
void pack_kernel(const float* __restrict__ W1, const float* __restrict__ b1,
                 const float* __restrict__ W2, const float* __restrict__ W3,
                 const float* __restrict__ Uq, const float* __restrict__ Ur,
                 unsigned char* __restrict__ ws)
{
    __bf16* w1p = (__bf16*)ws;
    __bf16* w2p = (__bf16*)(ws + 8192);
    __bf16* w3p = (__bf16*)(ws + 40960);
    __bf16* mp  = (__bf16*)(ws + 73728);
    const int d = blockIdx.x;   // 0..127
    const int t = threadIdx.x;  // 0..127
    if (t < 32) {
        float v = (t < 15) ? W1[d * 15 + t] : ((t == 15) ? b1[d] : 0.f);
        w1p[d * 32 + t] = (__bf16)v;
    }
    w2p[d * 128 + t] = (__bf16)W2[d * 128 + t];
    w3p[d * 128 + t] = (__bf16)W3[d * 128 + t];
    float acc = 0.f;
    for (int e = 0; e < 128; ++e)
        acc = fmaf(Ur[e * 128 + d], Uq[e * 128 + t], acc);
    mp[d * 128 + t] = (__bf16)acc;
}

__global__ __launch_bounds__(BLOCK, 4)
void fused_attn_kernel(const float* __restrict__ obs,
                       const float* __restrict__ b2g, const float* __restrict__ b3g,
                       const unsigned char* __restrict__ ws,
                       float* __restrict__ out)
{
    const __bf16* gW1 = (const __bf16*)ws;
    const __bf16* gW2 = (const __bf16*)(ws + 8192);
    const __bf16* gW3 = (const __bf16*)(ws + 40960);
    const __bf16* gM  = (const __bf16*)(ws + 73728);

    __shared__ __align__(16) __bf16 sX[128 * 128];  // x_real, [obj-row][e], swizzled
    __shared__ __align__(16) __bf16 sQ[16 * 128];   // q padded to 16 rows (4..15 zero)
    __shared__ __align__(16) float sV[4 * 128];     // v per batch row
    __shared__ float sLg[4 * 32];
    __shared__ float sWgt[4 * 32];
    __shared__ float sDp[8];

    const int tid  = threadIdx.x;
    const int lane = tid & 63;
    const int wv   = tid >> 6;      // 0..7
    const int l15  = lane & 15;
    const int kh   = lane >> 4;     // 0..3
    const int h    = wv & 1;        // object-half of its batch row
    const int brow = wv >> 1;       // batch row within iter (0..3)
    const bool khHi = ((kh >> 1) & 1) != 0;
    const int addrA = ((kh & 1) * 32 + l15) * 4;   // bpermute byte addr
    const int addrB = addrA + 64;

    // zero sQ once (rows 4..15 must stay 0 for the padded G-GEMM)
    for (int i = tid; i < 16 * 128; i += BLOCK) sQ[i] = (__bf16)0.f;

    // builds the next layer's B-fragment (k = d of prev layer) from transposed acc
    auto make_bfrag = [&](const f32x4 (&src)[8], int kk) -> bf16x8 {
        const int m0 = 2 * kk, m1 = 2 * kk + 1;
        int p00 = cvt_pk_bf16(src[m0][0], src[m0][1]);
        int p01 = cvt_pk_bf16(src[m0][2], src[m0][3]);
        int p10 = cvt_pk_bf16(src[m1][0], src[m1][1]);
        int p11 = cvt_pk_bf16(src[m1][2], src[m1][3]);
        int a0 = __builtin_amdgcn_ds_bpermute(addrA, p00);
        int a1 = __builtin_amdgcn_ds_bpermute(addrA, p10);
        int b0 = __builtin_amdgcn_ds_bpermute(addrA, p01);
        int b1_ = __builtin_amdgcn_ds_bpermute(addrA, p11);
        int c0 = __builtin_amdgcn_ds_bpermute(addrB, p00);
        int c1 = __builtin_amdgcn_ds_bpermute(addrB, p10);
        int d0 = __builtin_amdgcn_ds_bpermute(addrB, p01);
        int d1 = __builtin_amdgcn_ds_bpermute(addrB, p11);
        i32x4 w;
        w.x = khHi ? a1 : a0;
        w.y = khHi ? b1_ : b0;
        w.z = khHi ? c1 : c0;
        w.w = khHi ? d1 : d0;
        return __builtin_bit_cast(bf16x8, w);
    };

    // transposed layer: dst[e][n] = bias[e] + sum_d Wg[e][d]*src[d][n]
    auto layer = [&](const f32x4 (&src)[8], f32x4 (&dst)[8],
                     const __bf16* __restrict__ Wg, const float* __restrict__ bg,
                     bool do_relu) {
        #pragma unroll
        for (int mt = 0; mt < 8; ++mt)
            dst[mt] = *(const f32x4*)&bg[mt * 16 + kh * 4];
        #pragma unroll
        for (int kk = 0; kk < 4; ++kk) {
            bf16x8 bfr = make_bfrag(src, kk);
            #pragma unroll
            for (int mt = 0; mt < 8; ++mt) {
                bf16x8 afr = *(const bf16x8*)&Wg[(mt * 16 + l15) * 128 + kk * 32 + kh * 8];
                dst[mt] = __builtin_amdgcn_mfma_f32_16x16x32_bf16(afr, bfr, dst[mt], 0, 0, 0);
            }
        }
        if (do_relu) {
            #pragma unroll
            for (int mt = 0; mt < 8; ++mt)
                #pragma unroll
                for (int r = 0; r < 4; ++r)
                    dst[mt][r] = fmaxf(dst[mt][r], 0.f);
        }
    };

    for (int g = 0; g < ITERS; ++g) {
        const int row0 = blockIdx.x * (4 * ITERS) + g * 4;
        const int rb   = row0 + brow;
        const int nloc = h * 16 + l15;     // object index within batch row (0..31)

        f32x4 accA[8], accB[8];
        float mk;          // this lane's object mask
        {
            // ---- L1: D1[d][n] = relu( W1p[d][:] . featsT[:][n] ), bias folded ----
            bf16x8 bfr1;
            #pragma unroll
            for (int j = 0; j < 8; ++j) bfr1[j] = (__bf16)0.f;
            float maskv = 0.f;
            if (kh < 2) {
                const float* src = &obs[(size_t)rb * 576 + 32 + nloc * 16 + kh * 8];
                f32x4 u0 = *(const f32x4*)src;
                f32x4 u1 = *(const f32x4*)(src + 4);
                if (kh == 1) { maskv = u1.w; u1.w = 1.0f; }   // f15 -> bias channel
                bfr1[0] = (__bf16)u0.x; bfr1[1] = (__bf16)u0.y;
                bfr1[2] = (__bf16)u0.z; bfr1[3] = (__bf16)u0.w;
                bfr1[4] = (__bf16)u1.x; bfr1[5] = (__bf16)u1.y;
                bfr1[6] = (__bf16)u1.z; bfr1[7] = (__bf16)u1.w;
            }
            mk = __shfl(maskv, 16 + l15);   // mask lives at kh==1 lanes
            // per-wave mask half-sum -> sDp[wv]
            float t = (kh == 1) ? maskv : 0.f;
            t += __shfl_xor(t, 1);  t += __shfl_xor(t, 2);
            t += __shfl_xor(t, 4);  t += __shfl_xor(t, 8);
            t += __shfl_xor(t, 16); t += __shfl_xor(t, 32);
            if (lane == 0) sDp[wv] = t;

            #pragma unroll
            for (int mt = 0; mt < 8; ++mt) {
                bf16x8 afr = *(const bf16x8*)&gW1[(mt * 16 + l15) * 32 + kh * 8];
                f32x4 z = {0.f, 0.f, 0.f, 0.f};
                accA[mt] = __builtin_amdgcn_mfma_f32_16x16x32_bf16(afr, bfr1, z, 0, 0, 0);
            }
            #pragma unroll
            for (int mt = 0; mt < 8; ++mt)
                #pragma unroll
                for (int r = 0; r < 4; ++r)
                    accA[mt][r] = fmaxf(accA[mt][r], 0.f);
        }

        // ---- L2, L3 (transposed, registers only) ----
        layer(accA, accB, gW2, b2g, true);
        layer(accB, accA, gW3, b3g, false);

        // ---- mask multiply (column-uniform per lane) ----
        #pragma unroll
        for (int mt = 0; mt < 8; ++mt)
            #pragma unroll
            for (int r = 0; r < 4; ++r)
                accA[mt][r] *= mk;

        // ---- write x_real to sX[obj-row][e] (packed b64 writes) ----
        {
            const int m = brow * 32 + nloc;
            #pragma unroll
            for (int mt = 0; mt < 8; ++mt) {
                int e0 = mt * 16 + kh * 4;
                int pk0 = cvt_pk_bf16(accA[mt][0], accA[mt][1]);
                int pk1 = cvt_pk_bf16(accA[mt][2], accA[mt][3]);
                int2 pp; pp.x = pk0; pp.y = pk1;
                *(int2*)&sX[m * 128 + (e0 ^ ((m & 7) << 3))] = pp;
            }
        }
        __syncthreads();

        // ---- query colsum -> q (bf16, padded) ; aux passthrough ----
        {
            int b = tid >> 7, e = tid & 127;
            float s = 0.f;
            #pragma unroll
            for (int i = 0; i < 32; ++i)
                s += (float)sX[swz(b * 32 + i, e)];
            float rden = 1.f / (sDp[2 * b] + sDp[2 * b + 1] + 1e-5f);
            sQ[b * 128 + (e ^ (b << 3))] = (__bf16)(s * rden);
            if (tid < 256) {
                int r = tid >> 6, j = tid & 63;
                out[(size_t)(row0 + r) * 192 + j] =
                    (j < 32) ? obs[(size_t)(row0 + r) * 576 + j]
                             : obs[(size_t)(row0 + r) * 576 + 512 + j];
            }
        }
        __syncthreads();

        // ---- G: v[b][d] = sum_f q[b][f] * M[d][f]  (one MFMA slice per wave) ----
        {
            f32x4 acc = {0.f, 0.f, 0.f, 0.f};
            const int nt = wv;
            #pragma unroll
            for (int kk = 0; kk < 4; ++kk) {
                int kb = kk * 32 + kh * 8;
                bf16x8 a = *(const bf16x8*)&sQ[l15 * 128 + (kb ^ ((l15 & 7) << 3))];
                bf16x8 b = *(const bf16x8*)&gM[(nt * 16 + l15) * 128 + kb];
                acc = __builtin_amdgcn_mfma_f32_16x16x32_bf16(a, b, acc, 0, 0, 0);
            }
            if (kh == 0) {
                #pragma unroll
                for (int r = 0; r < 4; ++r)
                    sV[r * 128 + nt * 16 + l15] = acc[r];
            }
        }
        __syncthreads();

        // ---- logits per-lane from register x^T ----
        float lg;
        {
            float lp = 0.f;
            #pragma unroll
            for (int mt = 0; mt < 8; ++mt) {
                f32x4 vf = *(const f32x4*)&sV[brow * 128 + mt * 16 + kh * 4];
                #pragma unroll
                for (int r = 0; r < 4; ++r)
                    lp += vf[r] * accA[mt][r];
            }
            lp += __shfl_xor(lp, 16);
            lp += __shfl_xor(lp, 32);
            lg = lp + (1.f - mk) * (-1e9f);
            if (kh == 0) sLg[brow * 32 + nloc] = lg;
        }
        __syncthreads();

        // ---- softmax over 32 objects (pair of waves) ----
        {
            float ol = sLg[brow * 32 + (1 - h) * 16 + l15];
            float mx = fmaxf(lg, ol);
            #pragma unroll
            for (int off = 1; off < 16; off <<= 1) mx = fmaxf(mx, __shfl_xor(mx, off));
            float e0 = __expf(lg - mx), e1 = __expf(ol - mx);
            float ss = e0 + e1;
            #pragma unroll
            for (int off = 1; off < 16; off <<= 1) ss += __shfl_xor(ss, off);
            float w_own = e0 / ss;
            if (kh == 0) sWgt[brow * 32 + nloc] = w_own;
        }
        __syncthreads();

        // ---- out_att[b][e] = sum_n w[b][n] * x[b*32+n][e] ----
        {
            int b = tid >> 7, e = tid & 127;
            float a = 0.f;
            #pragma unroll
            for (int jj = 0; jj < 8; ++jj) {
                f32x4 w4 = *(const f32x4*)&sWgt[b * 32 + jj * 4];
                #pragma unroll
                for (int r = 0; r < 4; ++r)
                    a += w4[r] * (float)sX[swz(b * 32 + jj * 4 + r, e)];
            }
            out[(size_t)(row0 + b) * 192 + 64 + e] = a;
        }
        __syncthreads();   // protect LDS reuse next iteration
    }
}

extern "C" void kernel_launch(void* const* d_in, const int* in_sizes, int n_in,
                              void* d_out, int out_size, void* d_ws, size_t ws_size,
                              hipStream_t stream) {
    const float* obs = (const float*)d_in[0];
    const float* W1  = (const float*)d_in[1];
    const float* b1  = (const float*)d_in[2];
    const float* W2  = (const float*)d_in[3];
    const float* b2  = (const float*)d_in[4];
    const float* W3  = (const float*)d_in[5];
    const float* b3  = (const float*)d_in[6];
    const float* Uq  = (const float*)d_in[7];
    const float* Ur  = (const float*)d_in[8];
    float* out = (float*)d_out;
    unsigned char* ws = (unsigned char*)d_ws;

    pack_kernel<<<dim3(128), dim3(128), 0, stream>>>(W1, b1, W2, W3, Uq, Ur, ws);
    fused_attn_kernel<<<dim3(GRID), dim3(BLOCK), 0, stream>>>(
        obs, b2, b3, ws, out);
}

// Round 5
// 218.867 us; speedup vs baseline: 5.0181x; 5.0181x over previous
//
#include <hip/hip_runtime.h>

typedef __attribute__((ext_vector_type(8))) __bf16 bf16x8;
typedef __attribute__((ext_vector_type(4))) float f32x4;
typedef __attribute__((ext_vector_type(4))) int i32x4;

#define GRID 1024
#define BLOCK 512
#define ITERS 8   // 4 batch rows per iter -> 32 rows per block

// swizzle for 128-col bf16 LDS tiles
__device__ __forceinline__ int swz(int row, int col) {
    return row * 128 + (col ^ ((row & 7) << 3));
}

__device__ __forceinline__ int cvt_pk_bf16(float lo, float hi) {
    int r;
    asm("v_cvt_pk_bf16_f32 %0, %1, %2" : "=v"(r) : "v"(lo), "v"(hi));
    return r;
}

// ws layout (bytes):
//   0      : W1p bf16 [128][32]  (k<15: W1, k==15: b1 bias-fold, k>=16: 0), row-major
//   8192   : W2p bf16 [128][128] swz-swizzled  (row=out e, col=in d)
//   40960  : W3p bf16 [128][128] swz-swizzled
//   73728  : Mp  bf16 [128][128] row-major, M[d][f] = sum_e Ur[e][d]*Uq[e][f]
//   106496 : end

__global__ __launch_bounds__(128)
void pack_kernel(const float* __restrict__ W1, const float* __restrict__ b1,
                 const float* __restrict__ W2, const float* __restrict__ W3,
                 const float* __restrict__ Uq, const float* __restrict__ Ur,
                 unsigned char* __restrict__ ws)
{
    __bf16* w1p = (__bf16*)ws;
    __bf16* w2p = (__bf16*)(ws + 8192);
    __bf16* w3p = (__bf16*)(ws + 40960);
    __bf16* mp  = (__bf16*)(ws + 73728);
    const int d = blockIdx.x;   // 0..127 (row)
    const int t = threadIdx.x;  // 0..127 (col)
    if (t < 32) {
        float v = (t < 15) ? W1[d * 15 + t] : ((t == 15) ? b1[d] : 0.f);
        w1p[d * 32 + t] = (__bf16)v;
    }
    w2p[swz(d, t)] = (__bf16)W2[d * 128 + t];
    w3p[swz(d, t)] = (__bf16)W3[d * 128 + t];
    float acc = 0.f;
    for (int e = 0; e < 128; ++e)
        acc = fmaf(Ur[e * 128 + d], Uq[e * 128 + t], acc);
    mp[d * 128 + t] = (__bf16)acc;
}

__global__ __launch_bounds__(BLOCK, 2)
void fused_attn_kernel(const float* __restrict__ obs,
                       const float* __restrict__ b2g, const float* __restrict__ b3g,
                       const unsigned char* __restrict__ ws,
                       float* __restrict__ out)
{
    const __bf16* gW1 = (const __bf16*)ws;
    const __bf16* gW2 = (const __bf16*)(ws + 8192);
    const __bf16* gW3 = (const __bf16*)(ws + 40960);
    const __bf16* gM  = (const __bf16*)(ws + 73728);

    __shared__ __align__(16) __bf16 sW2[128 * 128];
    __shared__ __align__(16) __bf16 sW3[128 * 128];
    __shared__ __align__(16) __bf16 sX[128 * 128];  // x_real, [obj-row][e], swizzled
    __shared__ __align__(16) __bf16 sQ[16 * 128];   // q padded to 16 rows (4..15 zero)
    __shared__ __align__(16) float sV[4 * 128];     // v per batch row
    __shared__ float sLg[4 * 32];
    __shared__ float sWgt[4 * 32];
    __shared__ float sDp[8];

    const int tid  = threadIdx.x;
    const int lane = tid & 63;
    const int wv   = tid >> 6;      // 0..7
    const int l15  = lane & 15;
    const int kh   = lane >> 4;     // 0..3
    const int h    = wv & 1;        // object-half of its batch row
    const int brow = wv >> 1;       // batch row within iter (0..3)
    const bool khHi = ((kh >> 1) & 1) != 0;
    const int addrA = ((kh & 1) * 32 + l15) * 4;   // bpermute byte addr
    const int addrB = addrA + 64;

    // ---- stage pre-swizzled W2/W3 into LDS (linear b128 copies) ----
    for (int i = tid * 8; i < 128 * 128; i += BLOCK * 8) {
        *(bf16x8*)&sW2[i] = *(const bf16x8*)&gW2[i];
        *(bf16x8*)&sW3[i] = *(const bf16x8*)&gW3[i];
    }
    // zero sQ (rows 4..15 must stay 0 for the padded G-GEMM)
    for (int i = tid; i < 16 * 128; i += BLOCK) sQ[i] = (__bf16)0.f;

    // ---- per-block register-resident W1 A-frags and M B-frags (L2-hot, tiny) ----
    bf16x8 w1f[8];
    #pragma unroll
    for (int mt = 0; mt < 8; ++mt)
        w1f[mt] = *(const bf16x8*)&gW1[(mt * 16 + l15) * 32 + kh * 8];
    bf16x8 mf[4];
    #pragma unroll
    for (int kk = 0; kk < 4; ++kk)
        mf[kk] = *(const bf16x8*)&gM[(wv * 16 + l15) * 128 + kk * 32 + kh * 8];

    __syncthreads();

    // builds the next layer's B-fragment (k = d of prev layer) from transposed acc
    auto make_bfrag = [&](const f32x4 (&src)[8], int kk) -> bf16x8 {
        const int m0 = 2 * kk, m1 = 2 * kk + 1;
        int p00 = cvt_pk_bf16(src[m0][0], src[m0][1]);
        int p01 = cvt_pk_bf16(src[m0][2], src[m0][3]);
        int p10 = cvt_pk_bf16(src[m1][0], src[m1][1]);
        int p11 = cvt_pk_bf16(src[m1][2], src[m1][3]);
        int a0 = __builtin_amdgcn_ds_bpermute(addrA, p00);
        int a1 = __builtin_amdgcn_ds_bpermute(addrA, p10);
        int b0 = __builtin_amdgcn_ds_bpermute(addrA, p01);
        int b1_ = __builtin_amdgcn_ds_bpermute(addrA, p11);
        int c0 = __builtin_amdgcn_ds_bpermute(addrB, p00);
        int c1 = __builtin_amdgcn_ds_bpermute(addrB, p10);
        int d0 = __builtin_amdgcn_ds_bpermute(addrB, p01);
        int d1 = __builtin_amdgcn_ds_bpermute(addrB, p11);
        i32x4 w;
        w.x = khHi ? a1 : a0;
        w.y = khHi ? b1_ : b0;
        w.z = khHi ? c1 : c0;
        w.w = khHi ? d1 : d0;
        return __builtin_bit_cast(bf16x8, w);
    };

    // transposed layer: dst[e][n] = bias[e] + sum_d Ws[e][d]*src[d][n] ; Ws in LDS
    auto layer = [&](const f32x4 (&src)[8], f32x4 (&dst)[8],
                     const __bf16* __restrict__ Ws, const float* __restrict__ bg,
                     bool do_relu) {
        #pragma unroll
        for (int mt = 0; mt < 8; ++mt)
            dst[mt] = *(const f32x4*)&bg[mt * 16 + kh * 4];
        #pragma unroll
        for (int kk = 0; kk < 4; ++kk) {
            bf16x8 bfr = make_bfrag(src, kk);
            #pragma unroll
            for (int mt = 0; mt < 8; ++mt) {
                int row = mt * 16 + l15;
                bf16x8 afr = *(const bf16x8*)&Ws[row * 128 + ((kk * 32 + kh * 8) ^ ((row & 7) << 3))];
                dst[mt] = __builtin_amdgcn_mfma_f32_16x16x32_bf16(afr, bfr, dst[mt], 0, 0, 0);
            }
        }
        if (do_relu) {
            #pragma unroll
            for (int mt = 0; mt < 8; ++mt)
                #pragma unroll
                for (int r = 0; r < 4; ++r)
                    dst[mt][r] = fmaxf(dst[mt][r], 0.f);
        }
    };

    for (int g = 0; g < ITERS; ++g) {
        const int row0 = blockIdx.x * (4 * ITERS) + g * 4;
        const int rb   = row0 + brow;
        const int nloc = h * 16 + l15;     // object index within batch row (0..31)

        f32x4 accA[8], accB[8];
        float mk;          // this lane's object mask
        {
            // ---- L1: D1[d][n] = relu( W1p[d][:] . featsT[:][n] ), bias folded ----
            bf16x8 bfr1;
            #pragma unroll
            for (int j = 0; j < 8; ++j) bfr1[j] = (__bf16)0.f;
            float maskv = 0.f;
            if (kh < 2) {
                const float* src = &obs[(size_t)rb * 576 + 32 + nloc * 16 + kh * 8];
                f32x4 u0 = *(const f32x4*)src;
                f32x4 u1 = *(const f32x4*)(src + 4);
                if (kh == 1) { maskv = u1.w; u1.w = 1.0f; }   // f15 -> bias channel
                bfr1[0] = (__bf16)u0.x; bfr1[1] = (__bf16)u0.y;
                bfr1[2] = (__bf16)u0.z; bfr1[3] = (__bf16)u0.w;
                bfr1[4] = (__bf16)u1.x; bfr1[5] = (__bf16)u1.y;
                bfr1[6] = (__bf16)u1.z; bfr1[7] = (__bf16)u1.w;
            }
            mk = __shfl(maskv, 16 + l15);   // mask lives at kh==1 lanes
            // per-wave mask half-sum -> sDp[wv]
            float t = (kh == 1) ? maskv : 0.f;
            t += __shfl_xor(t, 1);  t += __shfl_xor(t, 2);
            t += __shfl_xor(t, 4);  t += __shfl_xor(t, 8);
            t += __shfl_xor(t, 16); t += __shfl_xor(t, 32);
            if (lane == 0) sDp[wv] = t;

            #pragma unroll
            for (int mt = 0; mt < 8; ++mt) {
                f32x4 z = {0.f, 0.f, 0.f, 0.f};
                accA[mt] = __builtin_amdgcn_mfma_f32_16x16x32_bf16(w1f[mt], bfr1, z, 0, 0, 0);
            }
            #pragma unroll
            for (int mt = 0; mt < 8; ++mt)
                #pragma unroll
                for (int r = 0; r < 4; ++r)
                    accA[mt][r] = fmaxf(accA[mt][r], 0.f);
        }

        // ---- L2, L3 (transposed; weights from LDS) ----
        layer(accA, accB, sW2, b2g, true);
        layer(accB, accA, sW3, b3g, false);

        // ---- mask multiply (column-uniform per lane) ----
        #pragma unroll
        for (int mt = 0; mt < 8; ++mt)
            #pragma unroll
            for (int r = 0; r < 4; ++r)
                accA[mt][r] *= mk;

        // ---- write x_real to sX[obj-row][e] (packed b64 writes) ----
        {
            const int m = brow * 32 + nloc;
            #pragma unroll
            for (int mt = 0; mt < 8; ++mt) {
                int e0 = mt * 16 + kh * 4;
                int pk0 = cvt_pk_bf16(accA[mt][0], accA[mt][1]);
                int pk1 = cvt_pk_bf16(accA[mt][2], accA[mt][3]);
                int2 pp; pp.x = pk0; pp.y = pk1;
                *(int2*)&sX[m * 128 + (e0 ^ ((m & 7) << 3))] = pp;
            }
        }
        __syncthreads();

        // ---- query colsum -> q (bf16, padded) ; aux passthrough ----
        {
            int b = tid >> 7, e = tid & 127;
            float s = 0.f;
            #pragma unroll
            for (int i = 0; i < 32; ++i)
                s += (float)sX[swz(b * 32 + i, e)];
            float rden = 1.f / (sDp[2 * b] + sDp[2 * b + 1] + 1e-5f);
            sQ[b * 128 + (e ^ (b << 3))] = (__bf16)(s * rden);
            if (tid < 256) {
                int r = tid >> 6, j = tid & 63;
                out[(size_t)(row0 + r) * 192 + j] =
                    (j < 32) ? obs[(size_t)(row0 + r) * 576 + j]
                             : obs[(size_t)(row0 + r) * 576 + 512 + j];
            }
        }
        __syncthreads();

        // ---- G: v[b][d] = sum_f q[b][f] * M[d][f]  (one MFMA slice per wave) ----
        {
            f32x4 acc = {0.f, 0.f, 0.f, 0.f};
            #pragma unroll
            for (int kk = 0; kk < 4; ++kk) {
                int kb = kk * 32 + kh * 8;
                bf16x8 a = *(const bf16x8*)&sQ[l15 * 128 + (kb ^ ((l15 & 7) << 3))];
                acc = __builtin_amdgcn_mfma_f32_16x16x32_bf16(a, mf[kk], acc, 0, 0, 0);
            }
            if (kh == 0) {
                #pragma unroll
                for (int r = 0; r < 4; ++r)
                    sV[r * 128 + wv * 16 + l15] = acc[r];
            }
        }
        __syncthreads();

        // ---- logits per-lane from register x^T ----
        float lg;
        {
            float lp = 0.f;
            #pragma unroll
            for (int mt = 0; mt < 8; ++mt) {
                f32x4 vf = *(const f32x4*)&sV[brow * 128 + mt * 16 + kh * 4];
                #pragma unroll
                for (int r = 0; r < 4; ++r)
                    lp += vf[r] * accA[mt][r];
            }
            lp += __shfl_xor(lp, 16);
            lp += __shfl_xor(lp, 32);
            lg = lp + (1.f - mk) * (-1e9f);
            if (kh == 0) sLg[brow * 32 + nloc] = lg;
        }
        __syncthreads();

        // ---- softmax over 32 objects (pair of waves) ----
        {
            float ol = sLg[brow * 32 + (1 - h) * 16 + l15];
            float mx = fmaxf(lg, ol);
            #pragma unroll
            for (int off = 1; off < 16; off <<= 1) mx = fmaxf(mx, __shfl_xor(mx, off));
            float e0 = __expf(lg - mx), e1 = __expf(ol - mx);
            float ss = e0 + e1;
            #pragma unroll
            for (int off = 1; off < 16; off <<= 1) ss += __shfl_xor(ss, off);
            float w_own = e0 / ss;
            if (kh == 0) sWgt[brow * 32 + nloc] = w_own;
        }
        __syncthreads();

        // ---- out_att[b][e] = sum_n w[b][n] * x[b*32+n][e] ----
        {
            int b = tid >> 7, e = tid & 127;
            float a = 0.f;
            #pragma unroll
            for (int jj = 0; jj < 8; ++jj) {
                f32x4 w4 = *(const f32x4*)&sWgt[b * 32 + jj * 4];
                #pragma unroll
                for (int r = 0; r < 4; ++r)
                    a += w4[r] * (float)sX[swz(b * 32 + jj * 4 + r, e)];
            }
            out[(size_t)(row0 + b) * 192 + 64 + e] = a;
        }
        __syncthreads();   // protect LDS reuse next iteration
    }
}

extern "C" void kernel_launch(void* const* d_in, const int* in_sizes, int n_in,
                              void* d_out, int out_size, void* d_ws, size_t ws_size,
                              hipStream_t stream) {
    const float* obs = (const float*)d_in[0];
    const float* W1  = (const float*)d_in[1];
    const float* b1  = (const float*)d_in[2];
    const float* W2  = (const float*)d_in[3];
    const float* b2  = (const float*)d_in[4];
    const float* W3  = (const float*)d_in[5];
    const float* b3  = (const float*)d_in[6];
    const float* Uq  = (const float*)d_in[7];
    const float* Ur  = (const float*)d_in[8];
    float* out = (float*)d_out;
    unsigned char* ws = (unsigned char*)d_ws;

    pack_kernel<<<dim3(128), dim3(128), 0, stream>>>(W1, b1, W2, W3, Uq, Ur, ws);
    fused_attn_kernel<<<dim3(GRID), dim3(BLOCK), 0, stream>>>(
        obs, b2, b3, ws, out);
}

// Round 6
// 111.642 us; speedup vs baseline: 9.8378x; 1.9604x over previous
//
#include <hip/hip_runtime.h>

typedef __attribute__((ext_vector_type(8))) __bf16 bf16x8;
typedef __attribute__((ext_vector_type(4))) float f32x4;
typedef __attribute__((ext_vector_type(16))) float f32x16;
typedef __attribute__((ext_vector_type(4))) int i32x4;

#define GRID 1024
#define BLOCK 512
#define ITERS 4   // 8 batch rows per iter -> 32 rows per block

__device__ __forceinline__ int swzi(int row, int col) {
    return row * 128 + (col ^ ((row & 7) << 3));
}
__device__ __forceinline__ int cvt_pk_bf16(float lo, float hi) {
    int r; asm("v_cvt_pk_bf16_f32 %0, %1, %2" : "=v"(r) : "v"(lo), "v"(hi)); return r;
}
__device__ __forceinline__ void pl32swap(int& a, int& b) {
    asm("v_permlane32_swap_b32 %0, %1" : "+v"(a), "+v"(b));
}
__device__ __forceinline__ void pl32swapf(float& a, float& b) {
    asm("v_permlane32_swap_b32 %0, %1" : "+v"(a), "+v"(b));
}
__device__ __forceinline__ float bflo(unsigned u) {
    unsigned v = u << 16; return __builtin_bit_cast(float, v);
}
__device__ __forceinline__ float bfhi(unsigned u) {
    unsigned v = u & 0xffff0000u; return __builtin_bit_cast(float, v);
}

// ws layout (bytes):
//   0     : W1p bf16 [128][16]  (k<15: W1, k==15: b1 bias-fold)
//   4096  : W2p bf16 [128][128] swzi-swizzled (row=out e, col=in d)
//   36864 : W3p bf16 [128][128] swzi-swizzled
//   69632 : Mp  bf16 [128][128] row-major, M[d][f] = sum_e Ur[e][d]*Uq[e][f]
__global__ __launch_bounds__(128)
void pack_kernel(const float* __restrict__ W1, const float* __restrict__ b1,
                 const float* __restrict__ W2, const float* __restrict__ W3,
                 const float* __restrict__ Uq, const float* __restrict__ Ur,
                 unsigned char* __restrict__ ws)
{
    __bf16* w1p = (__bf16*)ws;
    __bf16* w2p = (__bf16*)(ws + 4096);
    __bf16* w3p = (__bf16*)(ws + 36864);
    __bf16* mp  = (__bf16*)(ws + 69632);
    const int d = blockIdx.x, t = threadIdx.x;
    if (t < 16) w1p[d * 16 + t] = (__bf16)((t < 15) ? W1[d * 15 + t] : b1[d]);
    w2p[swzi(d, t)] = (__bf16)W2[d * 128 + t];
    w3p[swzi(d, t)] = (__bf16)W3[d * 128 + t];
    float acc = 0.f;
    for (int e = 0; e < 128; ++e)
        acc = fmaf(Ur[e * 128 + d], Uq[e * 128 + t], acc);
    mp[d * 128 + t] = (__bf16)acc;
}

__global__ __launch_bounds__(BLOCK, 2)
void fused_attn_kernel(const float* __restrict__ obs,
                       const float* __restrict__ b2g, const float* __restrict__ b3g,
                       const unsigned char* __restrict__ ws,
                       float* __restrict__ out)
{
    const __bf16* gW1 = (const __bf16*)ws;
    const __bf16* gW2 = (const __bf16*)(ws + 4096);
    const __bf16* gW3 = (const __bf16*)(ws + 36864);
    const __bf16* gM  = (const __bf16*)(ws + 69632);

    __shared__ __align__(16) __bf16 sW2[128 * 128];
    __shared__ __align__(16) __bf16 sW3[128 * 128];
    __shared__ __align__(16) __bf16 sX[256 * 128];   // x_real: 8 rows x 32 objs
    __shared__ __align__(16) __bf16 sQ[16 * 128];    // q padded to 16 rows
    __shared__ __align__(16) float sV[8 * 128];
    __shared__ __align__(16) float sB2[128], sB3[128];

    const int tid = threadIdx.x, lane = tid & 63, wv = tid >> 6;
    const int l31 = lane & 31, hi = lane >> 5;
    const int l15 = lane & 15, kh = lane >> 4;

    // ---- one-time staging ----
    for (int i = tid * 8; i < 128 * 128; i += BLOCK * 8) {
        *(bf16x8*)&sW2[i] = *(const bf16x8*)&gW2[i];
        *(bf16x8*)&sW3[i] = *(const bf16x8*)&gW3[i];
    }
    for (int i = tid; i < 16 * 128; i += BLOCK) sQ[i] = (__bf16)0.f;
    if (tid < 128) { sB2[tid] = b2g[tid]; sB3[tid] = b3g[tid]; }

    bf16x8 w1f[4];
    #pragma unroll
    for (int m = 0; m < 4; ++m)
        w1f[m] = *(const bf16x8*)&gW1[(m * 32 + l31) * 16 + hi * 8];
    bf16x8 mf[4];
    #pragma unroll
    for (int kk = 0; kk < 4; ++kk)
        mf[kk] = *(const bf16x8*)&gM[(wv * 16 + l15) * 128 + kk * 32 + kh * 8];
    __syncthreads();

    // transposed layer via 32x32x16: dst[e][n] = bias[e] + sum_d Ws[e][d]*src[d][n]
    auto layer32 = [&](const f32x16 (&src)[4], f32x16 (&dst)[4],
                       const __bf16* Ws, const float* sB, bool do_relu) {
        #pragma unroll
        for (int m = 0; m < 4; ++m) {
            f32x16 z;
            #pragma unroll
            for (int r = 0; r < 16; ++r) z[r] = 0.f;
            dst[m] = z;
        }
        #pragma unroll
        for (int kt = 0; kt < 8; ++kt) {
            const int ms = kt >> 1, b0 = (kt & 1) * 8;
            int Pa0 = cvt_pk_bf16(src[ms][b0 + 0], src[ms][b0 + 1]);
            int Pb0 = cvt_pk_bf16(src[ms][b0 + 2], src[ms][b0 + 3]);
            int Pa1 = cvt_pk_bf16(src[ms][b0 + 4], src[ms][b0 + 5]);
            int Pb1 = cvt_pk_bf16(src[ms][b0 + 6], src[ms][b0 + 7]);
            pl32swap(Pa0, Pa1);   // after: Pa0 = j0,1 word ; Pa1 = j4,5 word (all lanes)
            pl32swap(Pb0, Pb1);   // after: Pb0 = j2,3 word ; Pb1 = j6,7 word
            i32x4 wi; wi.x = Pa0; wi.y = Pb0; wi.z = Pa1; wi.w = Pb1;
            bf16x8 bfr = __builtin_bit_cast(bf16x8, wi);
            #pragma unroll
            for (int m = 0; m < 4; ++m) {
                int row = m * 32 + l31;
                bf16x8 afr = *(const bf16x8*)&Ws[row * 128 + ((kt * 16 + hi * 8) ^ ((row & 7) << 3))];
                dst[m] = __builtin_amdgcn_mfma_f32_32x32x16_bf16(afr, bfr, dst[m], 0, 0, 0);
            }
        }
        #pragma unroll
        for (int m = 0; m < 4; ++m)
            #pragma unroll
            for (int rg = 0; rg < 4; ++rg) {
                f32x4 bb = *(const f32x4*)&sB[m * 32 + rg * 8 + hi * 4];
                #pragma unroll
                for (int r = 0; r < 4; ++r) {
                    float v = dst[m][rg * 4 + r] + bb[r];
                    dst[m][rg * 4 + r] = do_relu ? fmaxf(v, 0.f) : v;
                }
            }
    };

    for (int g = 0; g < ITERS; ++g) {
        const int row0 = blockIdx.x * (8 * ITERS) + g * 8;
        const int rb   = row0 + wv;        // this wave's batch row
        const int xrow = wv * 32;          // its obj-row band in sX

        f32x16 acc1[4], acc2[4];
        float mk, rden;

        // ---- L1: feats direct from global as B-operand; bias folded via k=15 ----
        {
            const float* src = &obs[(size_t)rb * 576 + 32 + l31 * 16 + hi * 8];
            f32x4 u0 = *(const f32x4*)src;
            f32x4 u1 = *(const f32x4*)(src + 4);
            float maskv = 0.f;
            if (hi) { maskv = u1.w; u1.w = 1.0f; }   // feature15 = mask -> bias channel
            bf16x8 bfr;
            bfr[0] = (__bf16)u0.x; bfr[1] = (__bf16)u0.y;
            bfr[2] = (__bf16)u0.z; bfr[3] = (__bf16)u0.w;
            bfr[4] = (__bf16)u1.x; bfr[5] = (__bf16)u1.y;
            bfr[6] = (__bf16)u1.z; bfr[7] = (__bf16)u1.w;
            // mask to both halves: after swap(a,b) with a=b=maskv, b holds partner's (lo) / own (hi)
            float ma = maskv, mb = maskv;
            pl32swapf(ma, mb);
            mk = hi ? maskv : mb;
            float s = mk;
            s += __shfl_xor(s, 1);  s += __shfl_xor(s, 2);
            s += __shfl_xor(s, 4);  s += __shfl_xor(s, 8);
            s += __shfl_xor(s, 16);
            rden = 1.f / (s + 1e-5f);

            #pragma unroll
            for (int m = 0; m < 4; ++m) {
                f32x16 z;
                #pragma unroll
                for (int r = 0; r < 16; ++r) z[r] = 0.f;
                acc1[m] = __builtin_amdgcn_mfma_f32_32x32x16_bf16(w1f[m], bfr, z, 0, 0, 0);
                #pragma unroll
                for (int r = 0; r < 16; ++r) acc1[m][r] = fmaxf(acc1[m][r], 0.f);
            }
        }

        // ---- L2, L3 ----
        layer32(acc1, acc2, sW2, sB2, true);
        layer32(acc2, acc1, sW3, sB3, false);

        // ---- mask multiply -> x_real in acc1 ----
        #pragma unroll
        for (int m = 0; m < 4; ++m)
            #pragma unroll
            for (int r = 0; r < 16; ++r) acc1[m][r] *= mk;

        // ---- write x_real to sX (wave-private rows; b64 packed, XOR-swizzled) ----
        #pragma unroll
        for (int m = 0; m < 4; ++m)
            #pragma unroll
            for (int rg = 0; rg < 4; ++rg) {
                int pk0 = cvt_pk_bf16(acc1[m][rg * 4 + 0], acc1[m][rg * 4 + 1]);
                int pk1 = cvt_pk_bf16(acc1[m][rg * 4 + 2], acc1[m][rg * 4 + 3]);
                int e0 = m * 32 + rg * 8 + hi * 4;
                int row = xrow + l31;
                int2 pp; pp.x = pk0; pp.y = pk1;
                *(int2*)&sX[row * 128 + (e0 ^ ((row & 7) << 3))] = pp;
            }

        // ---- wave-local colsum -> q (in-wave RAW on sX, no barrier) ; aux out ----
        {
            float s0 = 0.f, s1 = 0.f;
            #pragma unroll
            for (int i = 0; i < 32; ++i) {
                int row = xrow + i;
                unsigned u = *(const unsigned*)&sX[row * 128 + ((2 * lane) ^ ((i & 7) << 3))];
                s0 += bflo(u); s1 += bfhi(u);
            }
            int qpk = cvt_pk_bf16(s0 * rden, s1 * rden);
            *(unsigned*)&sQ[wv * 128 + ((2 * lane) ^ (wv << 3))] = (unsigned)qpk;
            float av = (lane < 32) ? obs[(size_t)rb * 576 + lane]
                                   : obs[(size_t)rb * 576 + 512 + lane];
            out[(size_t)rb * 192 + lane] = av;
        }
        __syncthreads();   // B1: sQ ready for all waves

        // ---- G: v[row][d] = sum_f M[d][f] q[row][f] (each wave: 16-d slice, all rows) ----
        {
            f32x4 vac = {0.f, 0.f, 0.f, 0.f};
            #pragma unroll
            for (int kk = 0; kk < 4; ++kk) {
                bf16x8 a = *(const bf16x8*)&sQ[l15 * 128 + ((kk * 32 + kh * 8) ^ ((l15 & 7) << 3))];
                vac = __builtin_amdgcn_mfma_f32_16x16x32_bf16(a, mf[kk], vac, 0, 0, 0);
            }
            if (kh < 2) {
                #pragma unroll
                for (int r = 0; r < 4; ++r)
                    sV[(kh * 4 + r) * 128 + wv * 16 + l15] = vac[r];
            }
        }
        __syncthreads();   // B2: sV ready

        // ---- logits (register x), wave-local softmax, out_att ----
        {
            float lp = 0.f;
            #pragma unroll
            for (int m = 0; m < 4; ++m)
                #pragma unroll
                for (int rg = 0; rg < 4; ++rg) {
                    f32x4 vv = *(const f32x4*)&sV[wv * 128 + m * 32 + rg * 8 + hi * 4];
                    #pragma unroll
                    for (int r = 0; r < 4; ++r) lp = fmaf(vv[r], acc1[m][rg * 4 + r], lp);
                }
            float la = lp, lb = lp;
            pl32swapf(la, lb);                 // la: partner's (hi lanes), lb: partner's (lo lanes)
            float lpo = hi ? la : lb;
            float logit = lp + lpo + (1.f - mk) * (-1e9f);
            float mx = logit;
            mx = fmaxf(mx, __shfl_xor(mx, 1));  mx = fmaxf(mx, __shfl_xor(mx, 2));
            mx = fmaxf(mx, __shfl_xor(mx, 4));  mx = fmaxf(mx, __shfl_xor(mx, 8));
            mx = fmaxf(mx, __shfl_xor(mx, 16));
            float ex = __expf(logit - mx);
            float ss = ex;
            ss += __shfl_xor(ss, 1);  ss += __shfl_xor(ss, 2);
            ss += __shfl_xor(ss, 4);  ss += __shfl_xor(ss, 8);
            ss += __shfl_xor(ss, 16);
            float w = ex / ss;

            float o0 = 0.f, o1 = 0.f;
            int wb = __builtin_bit_cast(int, w);
            #pragma unroll
            for (int i = 0; i < 32; ++i) {
                float wi = __builtin_bit_cast(float, __builtin_amdgcn_readlane(wb, i));
                int row = xrow + i;
                unsigned u = *(const unsigned*)&sX[row * 128 + ((2 * lane) ^ ((i & 7) << 3))];
                o0 = fmaf(wi, bflo(u), o0);
                o1 = fmaf(wi, bfhi(u), o1);
            }
            float2 o; o.x = o0; o.y = o1;
            *(float2*)&out[(size_t)rb * 192 + 64 + 2 * lane] = o;
        }
        // no end barrier: next iter's B1/B2 order sQ/sV reuse; sX is wave-private
    }
}

extern "C" void kernel_launch(void* const* d_in, const int* in_sizes, int n_in,
                              void* d_out, int out_size, void* d_ws, size_t ws_size,
                              hipStream_t stream) {
    const float* obs = (const float*)d_in[0];
    const float* W1  = (const float*)d_in[1];
    const float* b1  = (const float*)d_in[2];
    const float* W2  = (const float*)d_in[3];
    const float* b2  = (const float*)d_in[4];
    const float* W3  = (const float*)d_in[5];
    const float* b3  = (const float*)d_in[6];
    const float* Uq  = (const float*)d_in[7];
    const float* Ur  = (const float*)d_in[8];
    float* out = (float*)d_out;
    unsigned char* ws = (unsigned char*)d_ws;

    pack_kernel<<<dim3(128), dim3(128), 0, stream>>>(W1, b1, W2, W3, Uq, Ur, ws);
    fused_attn_kernel<<<dim3(GRID), dim3(BLOCK), 0, stream>>>(
        obs, b2, b3, ws, out);
}